// Round 1
// 186.238 us; speedup vs baseline: 1.0353x; 1.0353x over previous
//
#include <hip/hip_runtime.h>
#include <math.h>

#define DT   0.1f
#define HDT  0.005f
#define T_HIST 20
#define LEN_PRED 30

typedef __attribute__((ext_vector_type(8))) short bfrag8;   // 8 bf16 = 4 VGPRs
typedef __attribute__((ext_vector_type(4))) float f32x4;
typedef __attribute__((ext_vector_type(2))) unsigned int u32x2;

// d_ws layout (bytes)
#define WS_FRAG   0u        // 96 frags * 512 bf16 * 2B = 98304
#define WS_WIN    98304u    // 2 frags * 1024B
#define WS_WOUT   100352u   // 1 frag * 1024B
#define WS_BIAS   101376u   // 2*3*128 floats = 3072B

static __device__ __forceinline__ unsigned short f2bf(float x) {
    union { float f; unsigned int u; } v; v.f = x;
    unsigned int r = v.u + 0x7fffu + ((v.u >> 16) & 1u);   // RNE
    return (unsigned short)(r >> 16);
}

static __device__ __forceinline__ unsigned int cvtpk(float lo, float hi) {
    unsigned int r;
    asm("v_cvt_pk_bf16_f32 %0, %1, %2" : "=v"(r) : "v"(lo), "v"(hi));
    return r;
}

// ---------------- weight prep: swizzle into row-permuted MFMA A-frag order ----------------
// Layer frag (ph,l,wv,j,c): tile-row p maps to W row gate*32+feat with
// gate = p&3, feat = wv*8 + (p>>2)*2 + j   (NEW mapping: lane's two j-features adjacent)
__global__ void prep_kernel(const float* __restrict__ Win_W,
                            const float* __restrict__ eWih, const float* __restrict__ eWhh,
                            const float* __restrict__ ebih, const float* __restrict__ ebhh,
                            const float* __restrict__ dWih, const float* __restrict__ dWhh,
                            const float* __restrict__ dbih, const float* __restrict__ dbhh,
                            const float* __restrict__ Wout_W,
                            char* __restrict__ ws)
{
    int i = blockIdx.x * blockDim.x + threadIdx.x;
    if (i < 49152) {
        int fi = i >> 9, within = i & 511;
        int lane = within >> 3, jj = within & 7;
        int c = fi & 1, j = (fi >> 1) & 1, wvv = (fi >> 2) & 3;
        int pl = fi >> 4;                 // ph*3 + l
        int l = pl % 3, ph = pl / 3;
        int p = lane & 15, q2 = lane >> 4;
        int gate = p & 3;
        int feat = wvv * 8 + (p >> 2) * 2 + j;       // NEW
        int row = gate * 32 + feat;
        int k = q2 * 8 + jj;
        const float* W = (c == 0) ? (ph ? dWih : eWih) : (ph ? dWhh : eWhh);
        ((unsigned short*)(ws + WS_FRAG))[i] = f2bf(W[l * 4096 + row * 32 + k]);
    } else if (i < 50176) {
        int i2 = i - 49152;
        int w = i2 >> 9, within = i2 & 511;
        int lane = within >> 3, jj = within & 7;
        int p = lane & 15, q2 = lane >> 4;
        int k = q2 * 8 + jj;
        float v = (k < 24) ? Win_W[(w * 16 + p) * 24 + k] : 0.f;
        ((unsigned short*)(ws + WS_WIN))[i2] = f2bf(v);
    } else if (i < 50688) {
        int i3 = i - 50176;
        int lane = i3 >> 3, jj = i3 & 7;
        int p = lane & 15, q2 = lane >> 4;
        float v = (p < 4) ? Wout_W[p * 32 + q2 * 8 + jj] : 0.f;
        ((unsigned short*)(ws + WS_WOUT))[i3] = f2bf(v);
    } else if (i < 51456) {
        int b = i - 50688;                 // combined biases bih+bhh
        int ph = b / 384, rem = b % 384;
        int l = rem >> 7, row = rem & 127;
        const float* bi = ph ? dbih : ebih;
        const float* bh = ph ? dbhh : ebhh;
        ((float*)(ws + WS_BIAS))[b] = bi[l * 128 + row] + bh[l * 128 + row];
    }
}

// ---------------- main kernel ----------------
// LDS layouts are feature-group-major: [fg][elem m][8 feats] so every B-frag
// read is lane*16B linear (conflict-free ds_read_b128).
__launch_bounds__(256, 2)
__global__ void kalman_lstm_kernel(const float* __restrict__ hist,
                                   const float* __restrict__ max_ax, const float* __restrict__ max_ay,
                                   const float* __restrict__ vstd, const float* __restrict__ astd,
                                   const float* __restrict__ Rx_, const float* __restrict__ Ry_,
                                   const float* __restrict__ Gx, const float* __restrict__ Gy,
                                   const float* __restrict__ Win_b, const float* __restrict__ Wout_b,
                                   const char* __restrict__ ws, float* __restrict__ out)
{
    __shared__ __align__(16) unsigned short xin[4][4][16][8];           // layer inputs (x0,c0,c1,c2)
    __shared__ __align__(16) unsigned short hbuf[2][3][4][16][8];       // double-buffered h
    __shared__ __align__(16) unsigned short xpw[2][4][16][8];           // decoder XP per Kalman wave
    __shared__ __align__(16) unsigned short xenc[T_HIST - 1][4][16][8]; // precomputed encoder x0
    __shared__ __align__(16) unsigned short xps[2][4][16][8];           // prologue XP staging

    const int tid  = threadIdx.x;
    const int wv   = tid >> 6;        // 0..3
    const int lane = tid & 63;
    const int q    = lane >> 4;
    const int m    = lane & 15;       // elem index
    const int b_elem = blockIdx.x * 16 + m;
    const f32x4 zero4 = {0.f, 0.f, 0.f, 0.f};

    // ---- per-phase layer weights in registers ----
    bfrag8 fragA[3][2][2];
    f32x4  biasV[3][2];               // bias folded into MFMA C-in
    const bfrag8* fragp = (const bfrag8*)(ws + WS_FRAG);
    const float*  combp = (const float*)(ws + WS_BIAS);
    auto load_phase = [&](int ph) {
#pragma unroll
        for (int l = 0; l < 3; ++l)
#pragma unroll
            for (int j = 0; j < 2; ++j) {
#pragma unroll
                for (int c = 0; c < 2; ++c) {
                    int fi = (((ph * 3 + l) * 4 + wv) * 2 + j) * 2 + c;
                    fragA[l][j][c] = fragp[fi * 64 + lane];
                }
#pragma unroll
                for (int r = 0; r < 4; ++r)
                    biasV[l][j][r] = combp[ph * 384 + l * 128 + r * 32 + (wv * 8 + q * 2 + j)];
            }
    };
    load_phase(0);

    // ---- Kalman-wave state (waves 2,3; channel ch = q&1, duplicated across q and q+2) ----
    bfrag8 winF = {}, woutF = {};
    f32x4 winB = {0.f, 0.f, 0.f, 0.f};
    float wb0 = 0.f, wb1 = 0.f, wb2 = 0.f, wb3 = 0.f;
    float g00 = 0.f, g01 = 0.f, g02 = 0.f, g11 = 0.f, g12 = 0.f, g22 = 0.f;   // G outer
    float qe00 = 0.f, qe01 = 0.f, qe02 = 0.f, qe11 = 0.f, qe12 = 0.f, qe22 = 0.f; // enc Q
    float Rch = 0.f, X0 = 0.f, X1 = 0.f, X2 = 0.f;
    float P00 = 0.f, P01 = 0.f, P02 = 0.f, P11 = 0.f, P12 = 0.f, P22 = 0.f;
    const int ch = q & 1;
    if (wv >= 2) {
        int w = wv - 2;
        winF  = ((const bfrag8*)(ws + WS_WIN))[w * 64 + lane];
        woutF = ((const bfrag8*)(ws + WS_WOUT))[lane];
#pragma unroll
        for (int r = 0; r < 4; ++r) winB[r] = Win_b[w * 16 + q * 4 + r];
        wb0 = Wout_b[0]; wb1 = Wout_b[1]; wb2 = Wout_b[2]; wb3 = Wout_b[3];
        const float rx = Rx_[0] * Rx_[0], ry = Ry_[0] * Ry_[0];
        Rch = ch ? ry : rx;
        float G0, G1, G2, sc;
        if (ch == 0) { G0 = Gx[0]; G1 = Gx[1]; G2 = Gx[2]; sc = max_ax[0]; }
        else         { G0 = Gy[0]; G1 = Gy[1]; G2 = Gy[2]; sc = max_ay[0]; }
        g00 = G0 * G0; g01 = G0 * G1; g02 = G0 * G2;
        g11 = G1 * G1; g12 = G1 * G2; g22 = G2 * G2;
        float s2 = sc * sc;
        qe00 = g00 * s2; qe01 = g01 * s2; qe02 = g02 * s2;
        qe11 = g11 * s2; qe12 = g12 * s2; qe22 = g22 * s2;
        X0 = hist[b_elem * (T_HIST * 2) + ch];
        // reference kinit uses R_x for P00 on BOTH channels
        P00 = rx; P11 = vstd[0] * vstd[0]; P22 = astd[0] * astd[0];
    }

    float creg[3][2];
#pragma unroll
    for (int l = 0; l < 3; ++l) { creg[l][0] = 0.f; creg[l][1] = 0.f; }

    // ---- LDS zero init (hbuf needs h=0; xpw fg=3 pad; xin for safety) ----
    for (int idx = tid; idx < 4 * 4 * 16 * 8; idx += 256) (&xin[0][0][0][0])[idx] = 0;
    for (int idx = tid; idx < 2 * 3 * 4 * 16 * 8; idx += 256) (&hbuf[0][0][0][0][0])[idx] = 0;
    for (int idx = tid; idx < 2 * 4 * 16 * 8; idx += 256) (&xpw[0][0][0][0])[idx] = 0;

    auto sig = [](float z) { return __builtin_amdgcn_rcpf(1.f + __expf(-z)); };
    auto th  = [](float z) { return fmaf(-2.f, __builtin_amdgcn_rcpf(__expf(2.f * z) + 1.f), 1.f); };

    auto kpred = [&](float Q00, float Q01, float Q02, float Q11, float Q12, float Q22) {
        X0 = X0 + DT * X1 + HDT * X2;
        X1 = X1 + DT * X2;
        float M00 = P00 + DT * P01 + HDT * P02;
        float M01 = P01 + DT * P11 + HDT * P12;
        float M02 = P02 + DT * P12 + HDT * P22;
        float M11 = P11 + DT * P12;
        float M12 = P12 + DT * P22;
        float M22 = P22;
        P00 = M00 + DT * M01 + HDT * M02 + Q00;
        P01 = M01 + DT * M02 + Q01;
        P02 = M02 + Q02;
        P11 = M11 + DT * M12 + Q11;
        P12 = M12 + Q12;
        P22 = M22 + Q22;
    };
    auto kupdate = [&](float z) {
        float y = z - X0;
        float Sinv = 1.0f / (P00 + Rch);
        float K0 = P00 * Sinv, K1 = P01 * Sinv, K2 = P02 * Sinv;
        X0 += y * K0; X1 += y * K1; X2 += y * K2;
        float p00 = P00, p01 = P01, p02 = P02;
        P00 = p00 - K0 * p00;
        P01 = p01 - K0 * p01;
        P02 = p02 - K0 * p02;
        P11 = P11 - K1 * p01;
        P12 = P12 - K1 * p02;
        P22 = P22 - K2 * p02;
    };
    // stage XP (feats 0..23) into a [4][16][8] fg-major buffer; q0/q1 lanes only
    auto stage_xp = [&](unsigned short (*buf)[16][8]) {
        if (q < 2) {
            auto wr = [&](int f, float v) { buf[f >> 3][m][f & 7] = f2bf(v); };
            int o = ch * 3;
            wr(o + 0, X0); wr(o + 1, X1); wr(o + 2, X2);
            int pb = 6 + ch * 9;
            wr(pb + 0, P00); wr(pb + 1, P01); wr(pb + 2, P02);
            wr(pb + 3, P01); wr(pb + 4, P11); wr(pb + 5, P12);
            wr(pb + 6, P02); wr(pb + 7, P12); wr(pb + 8, P22);
        }
    };

    // gates for one layer (all waves): a0/a1 hold the 4 gate pre-activations for
    // features wv*8+q*2 (+0,+1); packed c/h writes (1 dword each)
    auto gates = [&](int l, int pw, f32x4 a0, f32x4 a1) {
        float i0 = sig(a0[0]), f0 = sig(a0[1]), gg0 = th(a0[2]), o0 = sig(a0[3]);
        float c0 = fmaf(f0, creg[l][0], i0 * gg0);
        float h0 = o0 * th(c0);
        creg[l][0] = c0;
        float i1 = sig(a1[0]), f1 = sig(a1[1]), gg1 = th(a1[2]), o1 = sig(a1[3]);
        float c1 = fmaf(f1, creg[l][1], i1 * gg1);
        float h1 = o1 * th(c1);
        creg[l][1] = c1;
        *(unsigned int*)&xin[l + 1][wv][m][q * 2]    = cvtpk(c0, c1);
        *(unsigned int*)&hbuf[pw][l][wv][m][q * 2]   = cvtpk(h0, h1);
    };

    // ---- prologue: waves 2,3 run the whole encoder Kalman chain + Win, filling xenc.
    // Entirely wave-internal (same-wave LDS ordering) -> zero barriers. Waves 0,1 wait.
    if (wv >= 2) {
        const int w = wv - 2;
        for (int idx = lane; idx < 4 * 16 * 8; idx += 64) (&xps[w][0][0][0])[idx] = 0;
#pragma unroll 1
        for (int s = 0; s < T_HIST - 1; ++s) {
            if (s > 0) {
                float z = hist[b_elem * (T_HIST * 2) + s * 2 + ch];
                kpred(qe00, qe01, qe02, qe11, qe12, qe22);
                kupdate(z);
            }
            stage_xp(xps[w]);
            bfrag8 bxp = *(const bfrag8*)&xps[w][q][m][0];
            f32x4 aw = __builtin_amdgcn_mfma_f32_16x16x32_bf16(winF, bxp, zero4, 0, 0, 0);
            float v0 = th(aw[0] + winB[0]), v1 = th(aw[1] + winB[1]);
            float v2 = th(aw[2] + winB[2]), v3 = th(aw[3] + winB[3]);
            u32x2 pk; pk.x = cvtpk(v0, v1); pk.y = cvtpk(v2, v3);
            *(u32x2*)&xenc[s][w * 2 + (q >> 1)][m][(q & 1) * 4] = pk;
        }
        { // finish encoder with z_19 -> decoder-initial Kalman state (stays in regs)
            float z = hist[b_elem * (T_HIST * 2) + 19 * 2 + ch];
            kpred(qe00, qe01, qe02, qe11, qe12, qe22);
            kupdate(z);
        }
    }
    __syncthreads();     // prologue + zero init visible

    int p = 0;

    // ---- encoder: pure LSTM, 3 barriers/step, x0 comes from xenc ----
    for (int t = 0; t < T_HIST - 1; ++t) {
        f32x4 ah[3][2];
#pragma unroll
        for (int l = 0; l < 3; ++l) {           // hoisted h-MFMAs (hbuf[p] stable all step)
            bfrag8 bh = *(const bfrag8*)&hbuf[p][l][q][m][0];
            ah[l][0] = __builtin_amdgcn_mfma_f32_16x16x32_bf16(fragA[l][0][1], bh, biasV[l][0], 0, 0, 0);
            ah[l][1] = __builtin_amdgcn_mfma_f32_16x16x32_bf16(fragA[l][1][1], bh, biasV[l][1], 0, 0, 0);
        }
#pragma unroll
        for (int l = 0; l < 3; ++l) {
            bfrag8 bx = (l == 0) ? *(const bfrag8*)&xenc[t][q][m][0]
                                 : *(const bfrag8*)&xin[l][q][m][0];
            f32x4 a0 = __builtin_amdgcn_mfma_f32_16x16x32_bf16(fragA[l][0][0], bx, ah[l][0], 0, 0, 0);
            f32x4 a1 = __builtin_amdgcn_mfma_f32_16x16x32_bf16(fragA[l][1][0], bx, ah[l][1], 0, 0, 0);
            gates(l, p ^ 1, a0, a1);
            __syncthreads();
        }
        p ^= 1;
    }

    load_phase(1);

    // ---- decoder: waves 2,3 produce XP->x0 each step; 4 barriers/step ----
    for (int t = 0; t < LEN_PRED; ++t) {
        bfrag8 bc2;
        if (wv >= 2 && t > 0) bc2 = *(const bfrag8*)&xin[3][q][m][0];  // issue early
        f32x4 ah[3][2];
#pragma unroll
        for (int l = 0; l < 3; ++l) {
            bfrag8 bh = *(const bfrag8*)&hbuf[p][l][q][m][0];
            ah[l][0] = __builtin_amdgcn_mfma_f32_16x16x32_bf16(fragA[l][0][1], bh, biasV[l][0], 0, 0, 0);
            ah[l][1] = __builtin_amdgcn_mfma_f32_16x16x32_bf16(fragA[l][1][1], bh, biasV[l][1], 0, 0, 0);
        }
        if (wv >= 2) {
            const int w = wv - 2;
            if (t > 0) {       // decoder step t-1: pred from c2, Kalman pred, out store
                f32x4 ap = __builtin_amdgcn_mfma_f32_16x16x32_bf16(woutF, bc2, zero4, 0, 0, 0);
                float a0 = ap[0] + wb0, a1 = ap[1] + wb1, a2 = ap[2] + wb2, a3 = ap[3] + wb3;
                float s0 = __shfl(a0, m), s1 = __shfl(a1, m);
                float s2 = __shfl(a2, m), s3 = __shfl(a3, m);
                float pe = ch ? s1 : s0;
                float qe = ch ? s3 : s2;
                X2 = DT * pe;
                float qs = qe * qe;
                kpred(qs * g00, qs * g01, qs * g02, qs * g11, qs * g12, qs * g22);
                if (wv == 2 && q < 2) {
                    float* o = out + (size_t)b_elem * (LEN_PRED * 5) + (t - 1) * 5;
                    if (ch == 0) { o[0] = X0; o[2] = sqrtf(P00); }
                    else         { o[1] = X0; o[3] = sqrtf(P00); o[4] = 0.f; }
                }
            }
            stage_xp(xpw[w]);
            bfrag8 bxp = *(const bfrag8*)&xpw[w][q][m][0];
            f32x4 aw = __builtin_amdgcn_mfma_f32_16x16x32_bf16(winF, bxp, zero4, 0, 0, 0);
            float v0 = th(aw[0] + winB[0]), v1 = th(aw[1] + winB[1]);
            float v2 = th(aw[2] + winB[2]), v3 = th(aw[3] + winB[3]);
            u32x2 pk; pk.x = cvtpk(v0, v1); pk.y = cvtpk(v2, v3);
            *(u32x2*)&xin[0][w * 2 + (q >> 1)][m][(q & 1) * 4] = pk;
        }
        __syncthreads();
#pragma unroll
        for (int l = 0; l < 3; ++l) {
            bfrag8 bx = *(const bfrag8*)&xin[l][q][m][0];
            f32x4 a0 = __builtin_amdgcn_mfma_f32_16x16x32_bf16(fragA[l][0][0], bx, ah[l][0], 0, 0, 0);
            f32x4 a1 = __builtin_amdgcn_mfma_f32_16x16x32_bf16(fragA[l][1][0], bx, ah[l][1], 0, 0, 0);
            gates(l, p ^ 1, a0, a1);
            __syncthreads();
        }
        p ^= 1;
    }

    // epilogue: decoder step 29's pred + out (xin[3] stable since last barrier)
    if (wv == 2) {
        bfrag8 bc2 = *(const bfrag8*)&xin[3][q][m][0];
        f32x4 ap = __builtin_amdgcn_mfma_f32_16x16x32_bf16(woutF, bc2, zero4, 0, 0, 0);
        float a0 = ap[0] + wb0, a1 = ap[1] + wb1, a2 = ap[2] + wb2, a3 = ap[3] + wb3;
        float s0 = __shfl(a0, m), s1 = __shfl(a1, m);
        float s2 = __shfl(a2, m), s3 = __shfl(a3, m);
        float pe = ch ? s1 : s0;
        float qe = ch ? s3 : s2;
        X2 = DT * pe;
        float qs = qe * qe;
        kpred(qs * g00, qs * g01, qs * g02, qs * g11, qs * g12, qs * g22);
        if (q < 2) {
            float* o = out + (size_t)b_elem * (LEN_PRED * 5) + (LEN_PRED - 1) * 5;
            if (ch == 0) { o[0] = X0; o[2] = sqrtf(P00); }
            else         { o[1] = X0; o[3] = sqrtf(P00); o[4] = 0.f; }
        }
    }
}

extern "C" void kernel_launch(void* const* d_in, const int* in_sizes, int n_in,
                              void* d_out, int out_size, void* d_ws, size_t ws_size,
                              hipStream_t stream)
{
    const float* hist  = (const float*)d_in[0];
    const float* maxax = (const float*)d_in[1];
    const float* maxay = (const float*)d_in[2];
    const float* vstd  = (const float*)d_in[3];
    const float* astd  = (const float*)d_in[4];
    const float* Rx    = (const float*)d_in[5];
    const float* Ry    = (const float*)d_in[6];
    const float* Gx    = (const float*)d_in[7];
    const float* Gy    = (const float*)d_in[8];
    const float* WinW  = (const float*)d_in[9];
    const float* Winb  = (const float*)d_in[10];
    const float* eWih  = (const float*)d_in[11];
    const float* eWhh  = (const float*)d_in[12];
    const float* ebih  = (const float*)d_in[13];
    const float* ebhh  = (const float*)d_in[14];
    const float* dWih  = (const float*)d_in[15];
    const float* dWhh  = (const float*)d_in[16];
    const float* dbih  = (const float*)d_in[17];
    const float* dbhh  = (const float*)d_in[18];
    const float* WoutW = (const float*)d_in[19];
    const float* Woutb = (const float*)d_in[20];
    char* ws = (char*)d_ws;
    float* out = (float*)d_out;

    prep_kernel<<<202, 256, 0, stream>>>(WinW, eWih, eWhh, ebih, ebhh,
                                         dWih, dWhh, dbih, dbhh, WoutW, ws);
    kalman_lstm_kernel<<<512, 256, 0, stream>>>(hist, maxax, maxay, vstd, astd,
                                                Rx, Ry, Gx, Gy, Winb, Woutb,
                                                ws, out);
}